// Round 9
// baseline (1967.800 us; speedup 1.0000x reference)
//
#include <hip/hip_runtime.h>
#include <hip/hip_fp16.h>

// ============================================================================
// 2-layer LSTM (B=16384, T=128, F=12, H1=64, H2=128) + head, round 9.
// Changes vs R6 (881us best) / R8 (1555us, weight refetch):
//  - R=64 rows/block, 256 blocks = 1 block/CU, ONE grid round (R6 ran 4
//    serialized rounds). 4x work per barrier amortizes the ~45% bubble
//    fraction measured in R6 (4130cy/step vs ~2300cy issue).
//  - Weight footprint UNCHANGED vs R6 (60 regs): L0's 4 sequential 16x16
//    M-tiles share one coltile (12 regs); L1's 2 sequential 32x32 M-tiles
//    share one coltile (48 regs). R8's refetch came from 32x32 + interleave
//    pressure; here M-tiles are strictly sequential (one acc live at a time).
//  - hbuf/red alias dead st0/st1 LDS regions post-loop (96KB total static).
//  - All layouts (16x16, 32x32, qtrans4, prep) validated by R6/R8 absmax.
// ============================================================================

#define T_STEPS 128
#define F_IN    12
#define R       64      // batch rows per block

#define WF0_H8  (16*3*64)
#define WF1_H8  (16*12*64)                      // 16 coltiles x 12 ktiles (32x32x16)
#define WH_TOTAL_HALVES ((WF0_H8 + WF1_H8)*8)   // 245760 B

typedef _Float16 half8 __attribute__((ext_vector_type(8)));
typedef _Float16 half4 __attribute__((ext_vector_type(4)));
typedef float   floatx4  __attribute__((ext_vector_type(4)));
typedef float   floatx16 __attribute__((ext_vector_type(16)));
typedef int     intx4  __attribute__((ext_vector_type(4)));

__device__ __forceinline__ float vexp2(float x){
  float r; asm("v_exp_f32 %0, %1" : "=v"(r) : "v"(x)); return r;
}
__device__ __forceinline__ float vrcp(float x){
  float r; asm("v_rcp_f32 %0, %1" : "=v"(r) : "v"(x)); return r;
}
__device__ __forceinline__ float sigf(float x){        // sigmoid
  return vrcp(1.0f + vexp2(-1.4426950408889634f * x));
}
__device__ __forceinline__ float tanhf_(float x){      // tanh
  return fmaf(2.0f, vrcp(1.0f + vexp2(-2.8853900817779268f * x)), -1.0f);
}

// DPP quad_perm helpers.
__device__ __forceinline__ float qpx1(float v){
  return __int_as_float(__builtin_amdgcn_update_dpp(
      0, __float_as_int(v), 0xB1 /*[1,0,3,2]*/, 0xF, 0xF, true));
}
__device__ __forceinline__ float qpx2(float v){
  return __int_as_float(__builtin_amdgcn_update_dpp(
      0, __float_as_int(v), 0x4E /*[2,3,0,1]*/, 0xF, 0xF, true));
}
// 4x4 transpose across a lane quad (verified R4-R8): in s[j]=V(q,j), out d[j]=V(j,q).
__device__ __forceinline__ floatx4 qtrans4(floatx4 s, int g){
  float e0 = qpx1(s[1]), e1 = qpx1(s[0]), e2 = qpx1(s[3]), e3 = qpx1(s[2]);
  const bool lo = (g & 1);
  float m0 = lo ? e0   : s[0];
  float m1 = lo ? s[1] : e1;
  float m2 = lo ? e2   : s[2];
  float m3 = lo ? s[3] : e3;
  float f0 = qpx2(m2), f1 = qpx2(m3), f2 = qpx2(m0), f3 = qpx2(m1);
  const bool hi = (g & 2);
  floatx4 d;
  d[0] = hi ? f0 : m0;
  d[1] = hi ? f1 : m1;
  d[2] = hi ? m2 : f2;
  d[3] = hi ? m3 : f3;
  return d;
}

// ---------------------------------------------------------------------------
// Prep (identical to R8, correctness-validated): PERMUTED cols p=4h+g.
// L0: 16x16x32 frags [ct16][kt3][lane]: col=ct*16+(l&15), k=kt*32+(l>>4)*8+j
// L1: 32x32x16 frags [ct16][kt12][lane]: col=ct*32+(l&31), k=kt*16+(l>>5)*8+j
// ---------------------------------------------------------------------------
__global__ void prep_kernel(const float* __restrict__ Wih0, const float* __restrict__ Whh0,
                            const float* __restrict__ bih0, const float* __restrict__ bhh0,
                            const float* __restrict__ Wih1, const float* __restrict__ Whh1,
                            const float* __restrict__ bih1, const float* __restrict__ bhh1,
                            _Float16* __restrict__ wh, float* __restrict__ bs) {
  int tid = blockIdx.x * 256 + threadIdx.x;
  if (tid < WF0_H8) {
    int lane = tid & 63; int kt = (tid >> 6) % 3; int ct = tid / (64*3);
    int p = ct*16 + (lane & 15);
    int col = (p & 3)*64 + (p >> 2);
    int kbase = kt*32 + (lane >> 4)*8;
    #pragma unroll
    for (int j = 0; j < 8; ++j) {
      int k = kbase + j; float w = 0.0f;
      if (k < 12) w = Wih0[col*12 + k];
      else if (k < 76) w = Whh0[col*64 + (k-12)];
      wh[tid*8 + j] = (_Float16)w;
    }
  } else if (tid < WF0_H8 + WF1_H8) {
    int t2 = tid - WF0_H8;
    int lane = t2 & 63; int kt = (t2 >> 6) % 12; int ct = t2 / (64*12);
    int p = ct*32 + (lane & 31);
    int col = (p & 3)*128 + (p >> 2);
    int kbase = kt*16 + (lane >> 5)*8;
    #pragma unroll
    for (int j = 0; j < 8; ++j) {
      int k = kbase + j;
      float w = (k < 64) ? Wih1[col*64 + k] : Whh1[col*128 + (k-64)];
      wh[WF0_H8*8 + t2*8 + j] = (_Float16)w;
    }
  } else if (tid < WF0_H8 + WF1_H8 + 768) {
    int t3 = tid - (WF0_H8 + WF1_H8);
    if (t3 < 256) { int col = (t3 & 3)*64 + (t3 >> 2);  bs[t3] = bih0[col] + bhh0[col]; }
    else { int p1 = t3 - 256; int col = (p1 & 3)*128 + (p1 >> 2); bs[t3] = bih1[col] + bhh1[col]; }
  }
}

// ---------------------------------------------------------------------------
// Main: 1024 threads (16 waves), 64 rows/block, 256 blocks (1 round).
// st0[2][64][128]h: per row [x12|h0 64|zeros], XOR-swizzled 8-half blocks.
// st1[64][512]h:    per row [h0_p0 64|h0_p1 64|h1_p0 128|h1_p1 128].
// Wave w: L0 coltile w (4 seq M-tiles of 16 rows, shared 12-reg weights);
//         L1 coltile w 32x32 (2 seq M-tiles of 32 rows, shared 48-reg weights).
// ---------------------------------------------------------------------------
__global__ __launch_bounds__(1024, 1)
void lstm_kernel(const float* __restrict__ x, const _Float16* __restrict__ wh,
                 const float* __restrict__ bs,
                 const float* __restrict__ Wd1, const float* __restrict__ bd1,
                 const float* __restrict__ Wd2, const float* __restrict__ bd2,
                 float* __restrict__ out) {
  __shared__ __align__(16) char smem[32768 + 65536];      // 96 KB
  _Float16* st0 = (_Float16*)smem;                        // [2][64][128] halves
  _Float16* st1 = (_Float16*)(smem + 32768);              // [64][512] halves
  float*    hbuf = (float*)smem;                          // [64][128] alias, post-loop
  float*    red  = (float*)(smem + 32768);                // [64][16] alias, post-head

  const int tid  = threadIdx.x;
  const int w    = tid >> 6;
  const int lane = tid & 63;
  const int l15  = lane & 15;
  const int l31  = lane & 31;
  const int lg   = lane >> 4;            // 0..3
  const int hi5  = lane >> 5;            // 0..1
  const int qg   = lane & 3;             // quad index (gate slot)
  const int a    = l15 >> 2;
  const int r    = lg*4 + qg;            // L0 cell batch-row within M-tile
  const int rowbase = blockIdx.x * R;

  // Swizzled address helpers (halves).
  auto st0a = [](int buf, int row, int blk){
    return (buf*R + row)*128 + (((blk ^ (row & 7)) << 3)); };
  auto st0s = [](int buf, int row, int idx){
    return (buf*R + row)*128 + ((((idx >> 3) ^ (row & 7)) << 3) | (idx & 7)); };
  auto st1a = [](int row, int blk){
    return row*512 + (((blk ^ (row & 7)) << 3)); };
  auto st1s = [](int row, int idx){
    return row*512 + ((((idx >> 3) ^ (row & 7)) << 3) | (idx & 7)); };

  // ---- weights -> registers, pinned across the T loop (60 regs total) ----
  const intx4* whi = (const intx4*)wh;
  intx4 wb0i[3];
  #pragma unroll
  for (int kt = 0; kt < 3; ++kt) wb0i[kt] = whi[(w*3 + kt)*64 + lane];
  intx4 wb1i[12];
  #pragma unroll
  for (int kt = 0; kt < 12; ++kt) wb1i[kt] = whi[WF0_H8 + (w*12 + kt)*64 + lane];
  float b0  = bs[w*16 + l15];
  float b1v = bs[256 + w*32 + l31];

  // Register cell state: L0 4 cells (one per M-tile), L1 2x4 cells.
  float c0s[4]  = {0.0f, 0.0f, 0.0f, 0.0f};
  float c1m0[4] = {0.0f, 0.0f, 0.0f, 0.0f};
  float c1m1[4] = {0.0f, 0.0f, 0.0f, 0.0f};
  const int h0i = 4*w + a;               // L0 hidden owned by this lane
  const int h1w = 8*w + (l31 >> 2);      // L1 hidden owned by this lane

  // ---- zero-init LDS ----
  for (int i = tid; i < (2*R*128)/2; i += 1024) ((int*)st0)[i] = 0;
  for (int i = tid; i < (R*512)/2;   i += 1024) ((int*)st1)[i] = 0;
  __syncthreads();
  const int xr = tid / 3, xq = tid % 3;     // 192 threads stage x (64 rows x 3 quads)
  if (tid < 192) {
    float4 v0 = *(const float4*)&x[((size_t)(rowbase + xr)*T_STEPS + 0)*F_IN + xq*4];
    float4 v1 = *(const float4*)&x[((size_t)(rowbase + xr)*T_STEPS + 1)*F_IN + xq*4];
    half4 h40 = {(_Float16)v0.x, (_Float16)v0.y, (_Float16)v0.z, (_Float16)v0.w};
    half4 h41 = {(_Float16)v1.x, (_Float16)v1.y, (_Float16)v1.z, (_Float16)v1.w};
    *(half4*)&st0[st0s(0, xr, xq*4)] = h40;
    *(half4*)&st0[st0s(1, xr, xq*4)] = h41;
  }
  __syncthreads();

  // ---- layer-0 step (16x16) for M-tile mt (rows 16mt..16mt+15) ----
  auto do_A = [&](int tt, int mt, float& c0ref){
    const int pr = tt & 1;
    const int row16 = mt*16;
    floatx4 acc = {b0, b0, b0, b0};
    #pragma unroll
    for (int kt = 0; kt < 3; ++kt) {
      half8 af = *(const half8*)&st0[st0a(pr, row16 + l15, kt*4 + lg)];
      acc = __builtin_amdgcn_mfma_f32_16x16x32_f16(af, __builtin_bit_cast(half8, wb0i[kt]), acc, 0, 0, 0);
    }
    floatx4 d = qtrans4(acc, qg);
    c0ref = fmaf(sigf(d[1]), c0ref, sigf(d[0]) * tanhf_(d[2]));
    float h0v = sigf(d[3]) * tanhf_(c0ref);
    _Float16 hh = (_Float16)h0v;
    const int row = row16 + r;
    st0[st0s(pr^1, row, 12 + h0i)] = hh;
    st1[st1s(row, pr*64 + h0i)]    = hh;
  };

  // ---- layer-1 step (32x32x16) for M-tile mt (rows 32mt..32mt+31) ----
  auto do_C = [&](int tt, int mt, float (&c1p)[4]){
    const int pr = tt & 1;
    const int rb = mt*32;
    floatx16 acc;
    #pragma unroll
    for (int j = 0; j < 16; ++j) acc[j] = b1v;
    #pragma unroll
    for (int kt = 0; kt < 12; ++kt) {
      const int klog = kt*16 + hi5*8;
      const int idx  = (klog < 64) ? (pr*64 + klog)
                                   : (128 + (pr^1)*128 + (klog - 64));
      half8 af = *(const half8*)&st1[st1a(rb + l31, idx >> 3)];
      acc = __builtin_amdgcn_mfma_f32_32x32x16_f16(af, __builtin_bit_cast(half8, wb1i[kt]), acc, 0, 0, 0);
    }
    #pragma unroll
    for (int G = 0; G < 4; ++G) {
      floatx4 s = {acc[4*G+0], acc[4*G+1], acc[4*G+2], acc[4*G+3]};
      floatx4 d = qtrans4(s, qg);
      c1p[G] = fmaf(sigf(d[1]), c1p[G], sigf(d[0]) * tanhf_(d[2]));
      float h1v = sigf(d[3]) * tanhf_(c1p[G]);
      const int row = rb + 8*G + 4*hi5 + qg;
      st1[st1s(row, 128 + pr*128 + h1w)] = (_Float16)h1v;
      if (tt == T_STEPS - 1) hbuf[row*128 + h1w] = h1v;
    }
  };

  // ---- prologue: A(0) all 4 M-tiles; loop phases {C(t) || A(t+1)}, 1 barrier
  do_A(0, 0, c0s[0]); do_A(0, 1, c0s[1]); do_A(0, 2, c0s[2]); do_A(0, 3, c0s[3]);
  __syncthreads();

  for (int t = 0; t < T_STEPS; t += 2) {
    // Pin weights (forbid remat across the loop body).
    #pragma unroll
    for (int kt = 0; kt < 3; ++kt) asm volatile("" : "+v"(wb0i[kt]));
    #pragma unroll
    for (int kt = 0; kt < 12; ++kt) asm volatile("" : "+v"(wb1i[kt]));
    asm volatile("" : "+v"(b0), "+v"(b1v));

    #pragma unroll
    for (int hl = 0; hl < 2; ++hl) {
      const int tt = t + hl;
      const int pr = hl;               // tt & 1
      float4 xv = {0.0f, 0.0f, 0.0f, 0.0f};
      const bool dopre = (tt + 2 < T_STEPS);
      if (tid < 192 && dopre)          // issue x(tt+2) load early
        xv = *(const float4*)&x[((size_t)(rowbase + xr)*T_STEPS + (tt+2))*F_IN + xq*4];

      do_C(tt, 0, c1m0);
      do_C(tt, 1, c1m1);
      if (tt + 1 < T_STEPS) {
        do_A(tt+1, 0, c0s[0]); do_A(tt+1, 1, c0s[1]);
        do_A(tt+1, 2, c0s[2]); do_A(tt+1, 3, c0s[3]);
      }

      if (tid < 192 && dopre) {
        half4 h4 = {(_Float16)xv.x, (_Float16)xv.y, (_Float16)xv.z, (_Float16)xv.w};
        *(half4*)&st0[st0s(pr, xr, xq*4)] = h4;
      }
      __syncthreads();
    }
  }

  // ---------- Head: out[r] = b_d2 + Wd2 @ (b_d1 + Wd1 @ h1[r]) ----------
  {
    const int hr = tid & 63, jg = tid >> 6;   // 16 j-groups of 8
    float partial = 0.0f;
    #pragma unroll
    for (int jj = 0; jj < 8; ++jj) {
      int j = jg*8 + jj;
      float dacc = bd1[j];
      const float4* wrow = (const float4*)&Wd1[j*128];
      #pragma unroll 8
      for (int k4 = 0; k4 < 32; ++k4) {
        float4 wv = wrow[k4];
        const float4 hv = *(const float4*)&hbuf[hr*128 + k4*4];
        dacc = fmaf(wv.x, hv.x, dacc); dacc = fmaf(wv.y, hv.y, dacc);
        dacc = fmaf(wv.z, hv.z, dacc); dacc = fmaf(wv.w, hv.w, dacc);
      }
      partial = fmaf(Wd2[j], dacc, partial);
    }
    __syncthreads();                       // st1 reads all done; safe to alias red
    red[hr*16 + jg] = partial;
  }
  __syncthreads();
  if (tid < R) {
    float ssum = bd2[0];
    #pragma unroll
    for (int k = 0; k < 16; ++k) ssum += red[tid*16 + k];
    out[rowbase + tid] = ssum;
  }
}

extern "C" void kernel_launch(void* const* d_in, const int* in_sizes, int n_in,
                              void* d_out, int out_size, void* d_ws, size_t ws_size,
                              hipStream_t stream) {
  const float* x    = (const float*)d_in[0];
  const float* Wih0 = (const float*)d_in[1];
  const float* Whh0 = (const float*)d_in[2];
  const float* bih0 = (const float*)d_in[3];
  const float* bhh0 = (const float*)d_in[4];
  const float* Wih1 = (const float*)d_in[5];
  const float* Whh1 = (const float*)d_in[6];
  const float* bih1 = (const float*)d_in[7];
  const float* bhh1 = (const float*)d_in[8];
  const float* Wd1  = (const float*)d_in[9];
  const float* bd1  = (const float*)d_in[10];
  const float* Wd2  = (const float*)d_in[11];
  const float* bd2  = (const float*)d_in[12];
  float* out = (float*)d_out;

  _Float16* wh  = (_Float16*)d_ws;
  float*    bsv = (float*)((char*)d_ws + (size_t)WH_TOTAL_HALVES * 2);

  prep_kernel<<<63, 256, 0, stream>>>(Wih0, Whh0, bih0, bhh0, Wih1, Whh1, bih1, bhh1, wh, bsv);
  // 16384 rows / 64 per block = 256 blocks = exactly 1/CU, single round
  lstm_kernel<<<256, 1024, 0, stream>>>(x, wh, bsv, Wd1, bd1, Wd2, bd2, out);
}

// Round 10
// 873.322 us; speedup vs baseline: 2.2532x; 2.2532x over previous
//
#include <hip/hip_runtime.h>
#include <hip/hip_fp16.h>

// ============================================================================
// 2-layer LSTM (B=16384, T=128, F=12, H1=64, H2=128) + head, round 10.
// Model from R7-R9 failures: per-SIMD unified RF = 512 regs. 1024-thr blocks
// (4 waves/SIMD) cap waves at 128 regs -> 60 weight regs + 68 working = churn
// (R8/R9 FETCH blowup = weight refetch). FIX: 512-thr blocks, 8 waves/CU,
// 256 regs/wave. Each wave owns 2x columns: L0 2 coltiles (24 w-regs), L1 two
// 32x32 coltiles (96 w-regs) = 120 resident + ~130 free for acc/addr/state.
//  - R=32 rows/block, 512 blocks, 2 grid rounds.
//  - 1 barrier/timestep, phases {C(t) || A(t+1)} (R6 pipeline).
//  - XOR-swizzled LDS, DPP qtrans4, asm trans (all verified R6/R8).
// ============================================================================

#define T_STEPS 128
#define F_IN    12
#define R       32      // batch rows per block

#define WF0_H8  (16*3*64)
#define WF1_H8  (16*12*64)                      // 16 coltiles x 12 ktiles (32x32x16)
#define WH_TOTAL_HALVES ((WF0_H8 + WF1_H8)*8)   // 245760 B

typedef _Float16 half8 __attribute__((ext_vector_type(8)));
typedef _Float16 half4 __attribute__((ext_vector_type(4)));
typedef float   floatx4  __attribute__((ext_vector_type(4)));
typedef float   floatx16 __attribute__((ext_vector_type(16)));
typedef int     intx4  __attribute__((ext_vector_type(4)));

__device__ __forceinline__ float vexp2(float x){
  float r; asm("v_exp_f32 %0, %1" : "=v"(r) : "v"(x)); return r;
}
__device__ __forceinline__ float vrcp(float x){
  float r; asm("v_rcp_f32 %0, %1" : "=v"(r) : "v"(x)); return r;
}
__device__ __forceinline__ float sigf(float x){        // sigmoid
  return vrcp(1.0f + vexp2(-1.4426950408889634f * x));
}
__device__ __forceinline__ float tanhf_(float x){      // tanh
  return fmaf(2.0f, vrcp(1.0f + vexp2(-2.8853900817779268f * x)), -1.0f);
}

// DPP quad_perm helpers.
__device__ __forceinline__ float qpx1(float v){
  return __int_as_float(__builtin_amdgcn_update_dpp(
      0, __float_as_int(v), 0xB1 /*[1,0,3,2]*/, 0xF, 0xF, true));
}
__device__ __forceinline__ float qpx2(float v){
  return __int_as_float(__builtin_amdgcn_update_dpp(
      0, __float_as_int(v), 0x4E /*[2,3,0,1]*/, 0xF, 0xF, true));
}
// 4x4 transpose across a lane quad (verified R4-R9).
__device__ __forceinline__ floatx4 qtrans4(floatx4 s, int g){
  float e0 = qpx1(s[1]), e1 = qpx1(s[0]), e2 = qpx1(s[3]), e3 = qpx1(s[2]);
  const bool lo = (g & 1);
  float m0 = lo ? e0   : s[0];
  float m1 = lo ? s[1] : e1;
  float m2 = lo ? e2   : s[2];
  float m3 = lo ? s[3] : e3;
  float f0 = qpx2(m2), f1 = qpx2(m3), f2 = qpx2(m0), f3 = qpx2(m1);
  const bool hi = (g & 2);
  floatx4 d;
  d[0] = hi ? f0 : m0;
  d[1] = hi ? f1 : m1;
  d[2] = hi ? m2 : f2;
  d[3] = hi ? m3 : f3;
  return d;
}

// ---------------------------------------------------------------------------
// Prep (identical to R8/R9, correctness-validated): PERMUTED cols p=4h+g.
// L0: 16x16x32 frags [ct16][kt3][lane]: col=ct*16+(l&15), k=kt*32+(l>>4)*8+j
// L1: 32x32x16 frags [ct16][kt12][lane]: col=ct*32+(l&31), k=kt*16+(l>>5)*8+j
// ---------------------------------------------------------------------------
__global__ void prep_kernel(const float* __restrict__ Wih0, const float* __restrict__ Whh0,
                            const float* __restrict__ bih0, const float* __restrict__ bhh0,
                            const float* __restrict__ Wih1, const float* __restrict__ Whh1,
                            const float* __restrict__ bih1, const float* __restrict__ bhh1,
                            _Float16* __restrict__ wh, float* __restrict__ bs) {
  int tid = blockIdx.x * 256 + threadIdx.x;
  if (tid < WF0_H8) {
    int lane = tid & 63; int kt = (tid >> 6) % 3; int ct = tid / (64*3);
    int p = ct*16 + (lane & 15);
    int col = (p & 3)*64 + (p >> 2);
    int kbase = kt*32 + (lane >> 4)*8;
    #pragma unroll
    for (int j = 0; j < 8; ++j) {
      int k = kbase + j; float w = 0.0f;
      if (k < 12) w = Wih0[col*12 + k];
      else if (k < 76) w = Whh0[col*64 + (k-12)];
      wh[tid*8 + j] = (_Float16)w;
    }
  } else if (tid < WF0_H8 + WF1_H8) {
    int t2 = tid - WF0_H8;
    int lane = t2 & 63; int kt = (t2 >> 6) % 12; int ct = t2 / (64*12);
    int p = ct*32 + (lane & 31);
    int col = (p & 3)*128 + (p >> 2);
    int kbase = kt*16 + (lane >> 5)*8;
    #pragma unroll
    for (int j = 0; j < 8; ++j) {
      int k = kbase + j;
      float w = (k < 64) ? Wih1[col*64 + k] : Whh1[col*128 + (k-64)];
      wh[WF0_H8*8 + t2*8 + j] = (_Float16)w;
    }
  } else if (tid < WF0_H8 + WF1_H8 + 768) {
    int t3 = tid - (WF0_H8 + WF1_H8);
    if (t3 < 256) { int col = (t3 & 3)*64 + (t3 >> 2);  bs[t3] = bih0[col] + bhh0[col]; }
    else { int p1 = t3 - 256; int col = (p1 & 3)*128 + (p1 >> 2); bs[t3] = bih1[col] + bhh1[col]; }
  }
}

// ---------------------------------------------------------------------------
// Main: 512 threads (8 waves), 32 rows/block, 512 blocks (2 rounds, 1/CU).
// st0[2][32][128]h: per row [x12|h0 64|zeros], XOR-swizzled 8-half blocks.
// st1[32][512]h:    per row [h0_p0 64|h0_p1 64|h1_p0 128|h1_p1 128].
// Wave w: L0 coltiles {2w,2w+1} x M-tiles {0,1} (24 w-regs, shared);
//         L1 32x32 coltiles {2w,2w+1}, 32 rows (96 w-regs).
// ---------------------------------------------------------------------------
__global__ __launch_bounds__(512, 1)
void lstm_kernel(const float* __restrict__ x, const _Float16* __restrict__ wh,
                 const float* __restrict__ bs,
                 const float* __restrict__ Wd1, const float* __restrict__ bd1,
                 const float* __restrict__ Wd2, const float* __restrict__ bd2,
                 float* __restrict__ out) {
  __shared__ __align__(16) _Float16 st0[2*R*128];   // 16384 B
  __shared__ __align__(16) _Float16 st1[R*512];     // 32768 B
  __shared__ float hbuf[R*132];                     // 16896 B
  __shared__ float red[R*17];                       // 2176 B  -> ~68 KB

  const int tid  = threadIdx.x;
  const int w    = tid >> 6;             // 0..7
  const int lane = tid & 63;
  const int l15  = lane & 15;
  const int l31  = lane & 31;
  const int lg   = lane >> 4;            // 0..3
  const int hi5  = lane >> 5;            // 0..1
  const int qg   = lane & 3;             // quad index (gate slot)
  const int a    = l15 >> 2;
  const int r    = lg*4 + qg;            // L0 cell batch-row within M-tile
  const int rowbase = blockIdx.x * R;

  // Swizzled address helpers (halves).
  auto st0a = [](int buf, int row, int blk){
    return (buf*R + row)*128 + (((blk ^ (row & 7)) << 3)); };
  auto st0s = [](int buf, int row, int idx){
    return (buf*R + row)*128 + ((((idx >> 3) ^ (row & 7)) << 3) | (idx & 7)); };
  auto st1a = [](int row, int blk){
    return row*512 + (((blk ^ (row & 7)) << 3)); };
  auto st1s = [](int row, int idx){
    return row*512 + ((((idx >> 3) ^ (row & 7)) << 3) | (idx & 7)); };

  // ---- weights -> registers (120 regs), pinned across the T loop ----
  const intx4* whi = (const intx4*)wh;
  intx4 wb0i[2][3];
  #pragma unroll
  for (int i = 0; i < 2; ++i)
    #pragma unroll
    for (int kt = 0; kt < 3; ++kt) wb0i[i][kt] = whi[((2*w+i)*3 + kt)*64 + lane];
  intx4 wb1i[2][12];
  #pragma unroll
  for (int i = 0; i < 2; ++i)
    #pragma unroll
    for (int kt = 0; kt < 12; ++kt) wb1i[i][kt] = whi[WF0_H8 + ((2*w+i)*12 + kt)*64 + lane];
  float b0[2], b1[2];
  #pragma unroll
  for (int i = 0; i < 2; ++i) b0[i] = bs[(2*w+i)*16 + l15];
  #pragma unroll
  for (int i = 0; i < 2; ++i) b1[i] = bs[256 + (2*w+i)*32 + l31];

  // Cell state: L0 2ct x 2mt = 4; L1 2ct x 4G = 8.
  float c0s[2][2] = {{0.0f,0.0f},{0.0f,0.0f}};
  float c1s[2][4] = {{0.0f,0.0f,0.0f,0.0f},{0.0f,0.0f,0.0f,0.0f}};

  // ---- zero-init LDS ----
  for (int i = tid; i < (2*R*128)/2; i += 512) ((int*)st0)[i] = 0;
  for (int i = tid; i < (R*512)/2;   i += 512) ((int*)st1)[i] = 0;
  __syncthreads();
  const int xr = tid / 3, xq = tid % 3;     // 96 threads stage x
  if (tid < 96) {
    float4 v0 = *(const float4*)&x[((size_t)(rowbase + xr)*T_STEPS + 0)*F_IN + xq*4];
    float4 v1 = *(const float4*)&x[((size_t)(rowbase + xr)*T_STEPS + 1)*F_IN + xq*4];
    half4 h40 = {(_Float16)v0.x, (_Float16)v0.y, (_Float16)v0.z, (_Float16)v0.w};
    half4 h41 = {(_Float16)v1.x, (_Float16)v1.y, (_Float16)v1.z, (_Float16)v1.w};
    *(half4*)&st0[st0s(0, xr, xq*4)] = h40;
    *(half4*)&st0[st0s(1, xr, xq*4)] = h41;
  }
  __syncthreads();

  // ---- layer-0 step (16x16), coltile index i (ct=2w+i), M-tile mt ----
  auto do_A = [&](int tt, int i, int mt){
    const int pr = tt & 1;
    const int row16 = mt*16;
    const int ct = 2*w + i;
    floatx4 acc = {b0[i], b0[i], b0[i], b0[i]};
    #pragma unroll
    for (int kt = 0; kt < 3; ++kt) {
      half8 af = *(const half8*)&st0[st0a(pr, row16 + l15, kt*4 + lg)];
      acc = __builtin_amdgcn_mfma_f32_16x16x32_f16(af, __builtin_bit_cast(half8, wb0i[i][kt]), acc, 0, 0, 0);
    }
    floatx4 d = qtrans4(acc, qg);
    float c = fmaf(sigf(d[1]), c0s[i][mt], sigf(d[0]) * tanhf_(d[2]));
    c0s[i][mt] = c;
    float h0v = sigf(d[3]) * tanhf_(c);
    _Float16 hh = (_Float16)h0v;
    const int row = row16 + r;
    const int h0i = 4*ct + a;            // hidden unit owned by this lane
    st0[st0s(pr^1, row, 12 + h0i)] = hh;
    st1[st1s(row, pr*64 + h0i)]    = hh;
  };

  // ---- layer-1 step (32x32x16), coltile index i (ct=2w+i), 32 rows ----
  auto do_C = [&](int tt, int i){
    const int pr = tt & 1;
    const int ct = 2*w + i;
    floatx16 acc;
    #pragma unroll
    for (int j = 0; j < 16; ++j) acc[j] = b1[i];
    #pragma unroll
    for (int kt = 0; kt < 12; ++kt) {
      const int klog = kt*16 + hi5*8;
      const int idx  = (klog < 64) ? (pr*64 + klog)
                                   : (128 + (pr^1)*128 + (klog - 64));
      half8 af = *(const half8*)&st1[st1a(l31, idx >> 3)];
      acc = __builtin_amdgcn_mfma_f32_32x32x16_f16(af, __builtin_bit_cast(half8, wb1i[i][kt]), acc, 0, 0, 0);
    }
    const int h1w = 8*ct + (l31 >> 2);   // hidden unit owned by this lane
    #pragma unroll
    for (int G = 0; G < 4; ++G) {
      floatx4 s = {acc[4*G+0], acc[4*G+1], acc[4*G+2], acc[4*G+3]};
      floatx4 d = qtrans4(s, qg);
      float c = fmaf(sigf(d[1]), c1s[i][G], sigf(d[0]) * tanhf_(d[2]));
      c1s[i][G] = c;
      float h1v = sigf(d[3]) * tanhf_(c);
      const int row = 8*G + 4*hi5 + qg;
      st1[st1s(row, 128 + pr*128 + h1w)] = (_Float16)h1v;
      if (tt == T_STEPS - 1) hbuf[row*132 + h1w] = h1v;
    }
  };

  // ---- prologue: A(0) all 4 jobs; loop phases {C(t) || A(t+1)}, 1 barrier ----
  do_A(0, 0, 0); do_A(0, 0, 1); do_A(0, 1, 0); do_A(0, 1, 1);
  __syncthreads();

  for (int t = 0; t < T_STEPS; t += 2) {
    // Pin weights (forbid remat across the loop body).
    #pragma unroll
    for (int i = 0; i < 2; ++i) {
      #pragma unroll
      for (int kt = 0; kt < 3; ++kt) asm volatile("" : "+v"(wb0i[i][kt]));
      #pragma unroll
      for (int kt = 0; kt < 12; ++kt) asm volatile("" : "+v"(wb1i[i][kt]));
    }
    asm volatile("" : "+v"(b0[0]), "+v"(b0[1]), "+v"(b1[0]), "+v"(b1[1]));

    #pragma unroll
    for (int hl = 0; hl < 2; ++hl) {
      const int tt = t + hl;
      const int pr = hl;               // tt & 1
      float4 xv = {0.0f, 0.0f, 0.0f, 0.0f};
      const bool dopre = (tt + 2 < T_STEPS);
      if (tid < 96 && dopre)           // issue x(tt+2) load early
        xv = *(const float4*)&x[((size_t)(rowbase + xr)*T_STEPS + (tt+2))*F_IN + xq*4];

      do_C(tt, 0);
      do_C(tt, 1);
      if (tt + 1 < T_STEPS) {
        do_A(tt+1, 0, 0); do_A(tt+1, 0, 1);
        do_A(tt+1, 1, 0); do_A(tt+1, 1, 1);
      }

      if (tid < 96 && dopre) {
        half4 h4 = {(_Float16)xv.x, (_Float16)xv.y, (_Float16)xv.z, (_Float16)xv.w};
        *(half4*)&st0[st0s(pr, xr, xq*4)] = h4;
      }
      __syncthreads();
    }
  }

  // ---------- Head: out[r] = b_d2 + Wd2 @ (b_d1 + Wd1 @ h1[r]) ----------
  {
    const int hr = tid & 31, jg = tid >> 5;   // 16 j-groups of 8
    float partial = 0.0f;
    #pragma unroll
    for (int jj = 0; jj < 8; ++jj) {
      int j = jg*8 + jj;
      float dacc = bd1[j];
      const float4* wrow = (const float4*)&Wd1[j*128];
      #pragma unroll 8
      for (int k4 = 0; k4 < 32; ++k4) {
        float4 wv = wrow[k4];
        const float4 hv = *(const float4*)&hbuf[hr*132 + k4*4];
        dacc = fmaf(wv.x, hv.x, dacc); dacc = fmaf(wv.y, hv.y, dacc);
        dacc = fmaf(wv.z, hv.z, dacc); dacc = fmaf(wv.w, hv.w, dacc);
      }
      partial = fmaf(Wd2[j], dacc, partial);
    }
    red[hr*17 + jg] = partial;
  }
  __syncthreads();
  if (tid < R) {
    float ssum = bd2[0];
    #pragma unroll
    for (int k = 0; k < 16; ++k) ssum += red[tid*17 + k];
    out[rowbase + tid] = ssum;
  }
}

extern "C" void kernel_launch(void* const* d_in, const int* in_sizes, int n_in,
                              void* d_out, int out_size, void* d_ws, size_t ws_size,
                              hipStream_t stream) {
  const float* x    = (const float*)d_in[0];
  const float* Wih0 = (const float*)d_in[1];
  const float* Whh0 = (const float*)d_in[2];
  const float* bih0 = (const float*)d_in[3];
  const float* bhh0 = (const float*)d_in[4];
  const float* Wih1 = (const float*)d_in[5];
  const float* Whh1 = (const float*)d_in[6];
  const float* bih1 = (const float*)d_in[7];
  const float* bhh1 = (const float*)d_in[8];
  const float* Wd1  = (const float*)d_in[9];
  const float* bd1  = (const float*)d_in[10];
  const float* Wd2  = (const float*)d_in[11];
  const float* bd2  = (const float*)d_in[12];
  float* out = (float*)d_out;

  _Float16* wh  = (_Float16*)d_ws;
  float*    bsv = (float*)((char*)d_ws + (size_t)WH_TOTAL_HALVES * 2);

  prep_kernel<<<63, 256, 0, stream>>>(Wih0, Whh0, bih0, bhh0, Wih1, Whh1, bih1, bhh1, wh, bsv);
  // 16384 rows / 32 per block = 512 blocks (2 rounds at 1 block/CU)
  lstm_kernel<<<512, 512, 0, stream>>>(x, wh, bsv, Wd1, bd1, Wd2, bd2, out);
}

// Round 11
// 840.222 us; speedup vs baseline: 2.3420x; 1.0394x over previous
//
#include <hip/hip_runtime.h>
#include <hip/hip_fp16.h>

// ============================================================================
// 2-layer LSTM (B=16384, T=128, F=12, H1=64, H2=128) + head, round 11.
// R10 post-mortem: VALU-issue-bound (VALUBusy 66%, ~5400cy/8185cy step).
// Changes vs R10 (873us):
//  - DEDUP A-frag loads: one ds_read feeds BOTH coltiles' MFMAs (36->18
//    reads/wave/step; compiler couldn't CSE across interleaved LDS writes).
//  - PADDED STRIDES instead of XOR swizzle: st0 stride 136h, st1 stride 520h
//    (1040B -> 4-bank row rotation, same ~4-way conflicts as XOR) and
//    parity-contiguous st1 [h0_p0|h1_p1|h0_p1|h1_p0]. Every LDS address =
//    one per-lane base + compile-time offset immediate; kills the ~300
//    VALU ops/step of XOR chains + hi5 cndmask ternaries.
//  - Same math, same order -> absmax expected bit-identical.
// Config (proven R10): 512 thr / 8 waves, R=32, 512 blocks, 256 regs/wave
// (128V+128A), weights 120 regs resident, 1 barrier/timestep.
// ============================================================================

#define T_STEPS 128
#define F_IN    12
#define R       32      // batch rows per block
#define S0H     136     // st0 row stride in halves (272B = 17*16B)
#define S1H     520     // st1 row stride in halves (1040B = 65*16B)

#define WF0_H8  (16*3*64)
#define WF1_H8  (16*12*64)                      // 16 coltiles x 12 ktiles (32x32x16)
#define WH_TOTAL_HALVES ((WF0_H8 + WF1_H8)*8)   // 245760 B

typedef _Float16 half8 __attribute__((ext_vector_type(8)));
typedef _Float16 half4 __attribute__((ext_vector_type(4)));
typedef float   floatx4  __attribute__((ext_vector_type(4)));
typedef float   floatx16 __attribute__((ext_vector_type(16)));
typedef int     intx4  __attribute__((ext_vector_type(4)));

__device__ __forceinline__ float vexp2(float x){
  float r; asm("v_exp_f32 %0, %1" : "=v"(r) : "v"(x)); return r;
}
__device__ __forceinline__ float vrcp(float x){
  float r; asm("v_rcp_f32 %0, %1" : "=v"(r) : "v"(x)); return r;
}
__device__ __forceinline__ float sigf(float x){        // sigmoid
  return vrcp(1.0f + vexp2(-1.4426950408889634f * x));
}
__device__ __forceinline__ float tanhf_(float x){      // tanh
  return fmaf(2.0f, vrcp(1.0f + vexp2(-2.8853900817779268f * x)), -1.0f);
}

// DPP quad_perm helpers.
__device__ __forceinline__ float qpx1(float v){
  return __int_as_float(__builtin_amdgcn_update_dpp(
      0, __float_as_int(v), 0xB1 /*[1,0,3,2]*/, 0xF, 0xF, true));
}
__device__ __forceinline__ float qpx2(float v){
  return __int_as_float(__builtin_amdgcn_update_dpp(
      0, __float_as_int(v), 0x4E /*[2,3,0,1]*/, 0xF, 0xF, true));
}
// 4x4 transpose across a lane quad (verified R4-R10).
__device__ __forceinline__ floatx4 qtrans4(floatx4 s, int g){
  float e0 = qpx1(s[1]), e1 = qpx1(s[0]), e2 = qpx1(s[3]), e3 = qpx1(s[2]);
  const bool lo = (g & 1);
  float m0 = lo ? e0   : s[0];
  float m1 = lo ? s[1] : e1;
  float m2 = lo ? e2   : s[2];
  float m3 = lo ? s[3] : e3;
  float f0 = qpx2(m2), f1 = qpx2(m3), f2 = qpx2(m0), f3 = qpx2(m1);
  const bool hi = (g & 2);
  floatx4 d;
  d[0] = hi ? f0 : m0;
  d[1] = hi ? f1 : m1;
  d[2] = hi ? m2 : f2;
  d[3] = hi ? m3 : f3;
  return d;
}

// ---------------------------------------------------------------------------
// Prep (identical to R8-R10, correctness-validated): PERMUTED cols p=4h+g.
// ---------------------------------------------------------------------------
__global__ void prep_kernel(const float* __restrict__ Wih0, const float* __restrict__ Whh0,
                            const float* __restrict__ bih0, const float* __restrict__ bhh0,
                            const float* __restrict__ Wih1, const float* __restrict__ Whh1,
                            const float* __restrict__ bih1, const float* __restrict__ bhh1,
                            _Float16* __restrict__ wh, float* __restrict__ bs) {
  int tid = blockIdx.x * 256 + threadIdx.x;
  if (tid < WF0_H8) {
    int lane = tid & 63; int kt = (tid >> 6) % 3; int ct = tid / (64*3);
    int p = ct*16 + (lane & 15);
    int col = (p & 3)*64 + (p >> 2);
    int kbase = kt*32 + (lane >> 4)*8;
    #pragma unroll
    for (int j = 0; j < 8; ++j) {
      int k = kbase + j; float w = 0.0f;
      if (k < 12) w = Wih0[col*12 + k];
      else if (k < 76) w = Whh0[col*64 + (k-12)];
      wh[tid*8 + j] = (_Float16)w;
    }
  } else if (tid < WF0_H8 + WF1_H8) {
    int t2 = tid - WF0_H8;
    int lane = t2 & 63; int kt = (t2 >> 6) % 12; int ct = t2 / (64*12);
    int p = ct*32 + (lane & 31);
    int col = (p & 3)*128 + (p >> 2);
    int kbase = kt*16 + (lane >> 5)*8;
    #pragma unroll
    for (int j = 0; j < 8; ++j) {
      int k = kbase + j;
      float w = (k < 64) ? Wih1[col*64 + k] : Whh1[col*128 + (k-64)];
      wh[WF0_H8*8 + t2*8 + j] = (_Float16)w;
    }
  } else if (tid < WF0_H8 + WF1_H8 + 768) {
    int t3 = tid - (WF0_H8 + WF1_H8);
    if (t3 < 256) { int col = (t3 & 3)*64 + (t3 >> 2);  bs[t3] = bih0[col] + bhh0[col]; }
    else { int p1 = t3 - 256; int col = (p1 & 3)*128 + (p1 >> 2); bs[t3] = bih1[col] + bhh1[col]; }
  }
}

// ---------------------------------------------------------------------------
// Main: 512 threads (8 waves), 32 rows/block, 512 blocks.
// st0[2][32][136]h: per row [x12|h0 64|zeros..95|pad]. Padded stride.
// st1[32][520]h: per row [h0_p0 @0 | h1_p1 @64 | h0_p1 @192 | h1_p0 @256].
//   Parity pr reads contiguous [pr*192 .. pr*192+191].
// Wave w: L0 coltiles {2w,2w+1} x M-tiles {0,1}; L1 32x32 coltiles {2w,2w+1}.
// ---------------------------------------------------------------------------
__global__ __launch_bounds__(512, 1)
void lstm_kernel(const float* __restrict__ x, const _Float16* __restrict__ wh,
                 const float* __restrict__ bs,
                 const float* __restrict__ Wd1, const float* __restrict__ bd1,
                 const float* __restrict__ Wd2, const float* __restrict__ bd2,
                 float* __restrict__ out) {
  __shared__ __align__(16) _Float16 st0[2*R*S0H];   // 17408 B
  __shared__ __align__(16) _Float16 st1[R*S1H];     // 33280 B
  __shared__ float hbuf[R*132];                     // 16896 B
  __shared__ float red[R*17];                       // 2176 B  -> ~70 KB

  const int tid  = threadIdx.x;
  const int w    = tid >> 6;             // 0..7
  const int lane = tid & 63;
  const int l15  = lane & 15;
  const int l31  = lane & 31;
  const int lg   = lane >> 4;            // 0..3
  const int hi5  = lane >> 5;            // 0..1
  const int qg   = lane & 3;             // quad index (gate slot)
  const int a    = l15 >> 2;
  const int u    = l31 >> 2;             // L1 hidden sub-index
  const int r    = lg*4 + qg;            // L0 cell batch-row within M-tile
  const int rowbase = blockIdx.x * R;

  // ---- weights -> registers (120 regs), pinned across the T loop ----
  const intx4* whi = (const intx4*)wh;
  intx4 wb0i[2][3];
  #pragma unroll
  for (int i = 0; i < 2; ++i)
    #pragma unroll
    for (int kt = 0; kt < 3; ++kt) wb0i[i][kt] = whi[((2*w+i)*3 + kt)*64 + lane];
  intx4 wb1i[2][12];
  #pragma unroll
  for (int i = 0; i < 2; ++i)
    #pragma unroll
    for (int kt = 0; kt < 12; ++kt) wb1i[i][kt] = whi[WF0_H8 + ((2*w+i)*12 + kt)*64 + lane];
  float b0[2], b1[2];
  #pragma unroll
  for (int i = 0; i < 2; ++i) b0[i] = bs[(2*w+i)*16 + l15];
  #pragma unroll
  for (int i = 0; i < 2; ++i) b1[i] = bs[256 + (2*w+i)*32 + l31];

  // Cell state: L0 2ct x 2mt; L1 2ct x 4G.
  float c0s[2][2] = {{0.0f,0.0f},{0.0f,0.0f}};
  float c1s[2][4] = {{0.0f,0.0f,0.0f,0.0f},{0.0f,0.0f,0.0f,0.0f}};

  // ---- per-lane LDS base indices (halves); everything else is immediate ----
  const int rdA0 = l15*S0H + lg*8;               // + pr*R*S0H + mt*16*S0H + kt*32
  const int rdA1 = l31*S1H + hi5*8;              // + pr*192 + kt*16
  const int wrH0st0 = r*S0H + 12 + 8*w + a;      // + (pr^1)*R*S0H + mt*16*S0H + 4*i
  const int wrH0st1 = r*S1H + 8*w + a;           // + mt*16*S1H + pr*192 + 4*i
  const int wrH1 = (4*hi5 + qg)*S1H + 16*w + u;  // + G*8*S1H + (pr?64:256) + 8*i

  // ---- zero-init LDS ----
  for (int i = tid; i < (2*R*S0H)/2; i += 512) ((int*)st0)[i] = 0;
  for (int i = tid; i < (R*S1H)/2;   i += 512) ((int*)st1)[i] = 0;
  __syncthreads();
  const int xr = tid / 3, xq = tid % 3;     // 96 threads stage x
  if (tid < 96) {
    float4 v0 = *(const float4*)&x[((size_t)(rowbase + xr)*T_STEPS + 0)*F_IN + xq*4];
    float4 v1 = *(const float4*)&x[((size_t)(rowbase + xr)*T_STEPS + 1)*F_IN + xq*4];
    half4 h40 = {(_Float16)v0.x, (_Float16)v0.y, (_Float16)v0.z, (_Float16)v0.w};
    half4 h41 = {(_Float16)v1.x, (_Float16)v1.y, (_Float16)v1.z, (_Float16)v1.w};
    *(half4*)&st0[xr*S0H + xq*4]           = h40;
    *(half4*)&st0[R*S0H + xr*S0H + xq*4]   = h41;
  }
  __syncthreads();

  // ---- layer-0 step (16x16), BOTH coltiles, M-tile mt; frags loaded once ----
  auto do_A = [&](int tt, int mt){
    const int pr = tt & 1;
    const int rbase = rdA0 + pr*(R*S0H) + mt*(16*S0H);
    floatx4 acc0 = {b0[0], b0[0], b0[0], b0[0]};
    floatx4 acc1 = {b0[1], b0[1], b0[1], b0[1]};
    #pragma unroll
    for (int kt = 0; kt < 3; ++kt) {
      half8 af = *(const half8*)&st0[rbase + kt*32];
      acc0 = __builtin_amdgcn_mfma_f32_16x16x32_f16(af, __builtin_bit_cast(half8, wb0i[0][kt]), acc0, 0, 0, 0);
      acc1 = __builtin_amdgcn_mfma_f32_16x16x32_f16(af, __builtin_bit_cast(half8, wb0i[1][kt]), acc1, 0, 0, 0);
    }
    #pragma unroll
    for (int i = 0; i < 2; ++i) {
      floatx4 d = qtrans4(i ? acc1 : acc0, qg);
      float c = fmaf(sigf(d[1]), c0s[i][mt], sigf(d[0]) * tanhf_(d[2]));
      c0s[i][mt] = c;
      float h0v = sigf(d[3]) * tanhf_(c);
      _Float16 hh = (_Float16)h0v;
      st0[wrH0st0 + (pr^1)*(R*S0H) + mt*(16*S0H) + 4*i] = hh;
      st1[wrH0st1 + mt*(16*S1H) + pr*192 + 4*i]          = hh;
    }
  };

  // ---- layer-1 step (32x32x16), BOTH coltiles, 32 rows; frags loaded once ----
  auto do_C = [&](int tt){
    const int pr = tt & 1;
    const int rbase = rdA1 + pr*192;
    floatx16 acc0, acc1;
    #pragma unroll
    for (int j = 0; j < 16; ++j) { acc0[j] = b1[0]; acc1[j] = b1[1]; }
    #pragma unroll
    for (int kt = 0; kt < 12; ++kt) {
      half8 af = *(const half8*)&st1[rbase + kt*16];
      acc0 = __builtin_amdgcn_mfma_f32_32x32x16_f16(af, __builtin_bit_cast(half8, wb1i[0][kt]), acc0, 0, 0, 0);
      acc1 = __builtin_amdgcn_mfma_f32_32x32x16_f16(af, __builtin_bit_cast(half8, wb1i[1][kt]), acc1, 0, 0, 0);
    }
    const int wbase = wrH1 + (pr ? 64 : 256);   // h1(pr) slot
    #pragma unroll
    for (int i = 0; i < 2; ++i) {
      #pragma unroll
      for (int G = 0; G < 4; ++G) {
        floatx4 s;
        if (i) { s[0]=acc1[4*G+0]; s[1]=acc1[4*G+1]; s[2]=acc1[4*G+2]; s[3]=acc1[4*G+3]; }
        else   { s[0]=acc0[4*G+0]; s[1]=acc0[4*G+1]; s[2]=acc0[4*G+2]; s[3]=acc0[4*G+3]; }
        floatx4 d = qtrans4(s, qg);
        float c = fmaf(sigf(d[1]), c1s[i][G], sigf(d[0]) * tanhf_(d[2]));
        c1s[i][G] = c;
        float h1v = sigf(d[3]) * tanhf_(c);
        st1[wbase + G*(8*S1H) + 8*i] = (_Float16)h1v;
        if (tt == T_STEPS - 1) {
          const int row = 8*G + 4*hi5 + qg;
          hbuf[row*132 + 16*w + 8*i + u] = h1v;
        }
      }
    }
  };

  // ---- prologue: A(0) both M-tiles; loop phases {C(t) || A(t+1)}, 1 barrier
  do_A(0, 0); do_A(0, 1);
  __syncthreads();

  for (int t = 0; t < T_STEPS; t += 2) {
    // Pin weights (forbid remat across the loop body).
    #pragma unroll
    for (int i = 0; i < 2; ++i) {
      #pragma unroll
      for (int kt = 0; kt < 3; ++kt) asm volatile("" : "+v"(wb0i[i][kt]));
      #pragma unroll
      for (int kt = 0; kt < 12; ++kt) asm volatile("" : "+v"(wb1i[i][kt]));
    }
    asm volatile("" : "+v"(b0[0]), "+v"(b0[1]), "+v"(b1[0]), "+v"(b1[1]));

    #pragma unroll
    for (int hl = 0; hl < 2; ++hl) {
      const int tt = t + hl;
      const int pr = hl;               // tt & 1
      float4 xv = {0.0f, 0.0f, 0.0f, 0.0f};
      const bool dopre = (tt + 2 < T_STEPS);
      if (tid < 96 && dopre)           // issue x(tt+2) load early
        xv = *(const float4*)&x[((size_t)(rowbase + xr)*T_STEPS + (tt+2))*F_IN + xq*4];

      do_C(tt);
      if (tt + 1 < T_STEPS) { do_A(tt+1, 0); do_A(tt+1, 1); }

      if (tid < 96 && dopre) {
        half4 h4 = {(_Float16)xv.x, (_Float16)xv.y, (_Float16)xv.z, (_Float16)xv.w};
        *(half4*)&st0[pr*(R*S0H) + xr*S0H + xq*4] = h4;
      }
      __syncthreads();
    }
  }

  // ---------- Head: out[r] = b_d2 + Wd2 @ (b_d1 + Wd1 @ h1[r]) ----------
  {
    const int hr = tid & 31, jg = tid >> 5;   // 16 j-groups of 8
    float partial = 0.0f;
    #pragma unroll
    for (int jj = 0; jj < 8; ++jj) {
      int j = jg*8 + jj;
      float dacc = bd1[j];
      const float4* wrow = (const float4*)&Wd1[j*128];
      #pragma unroll 8
      for (int k4 = 0; k4 < 32; ++k4) {
        float4 wv = wrow[k4];
        const float4 hv = *(const float4*)&hbuf[hr*132 + k4*4];
        dacc = fmaf(wv.x, hv.x, dacc); dacc = fmaf(wv.y, hv.y, dacc);
        dacc = fmaf(wv.z, hv.z, dacc); dacc = fmaf(wv.w, hv.w, dacc);
      }
      partial = fmaf(Wd2[j], dacc, partial);
    }
    red[hr*17 + jg] = partial;
  }
  __syncthreads();
  if (tid < R) {
    float ssum = bd2[0];
    #pragma unroll
    for (int k = 0; k < 16; ++k) ssum += red[tid*17 + k];
    out[rowbase + tid] = ssum;
  }
}

extern "C" void kernel_launch(void* const* d_in, const int* in_sizes, int n_in,
                              void* d_out, int out_size, void* d_ws, size_t ws_size,
                              hipStream_t stream) {
  const float* x    = (const float*)d_in[0];
  const float* Wih0 = (const float*)d_in[1];
  const float* Whh0 = (const float*)d_in[2];
  const float* bih0 = (const float*)d_in[3];
  const float* bhh0 = (const float*)d_in[4];
  const float* Wih1 = (const float*)d_in[5];
  const float* Whh1 = (const float*)d_in[6];
  const float* bih1 = (const float*)d_in[7];
  const float* bhh1 = (const float*)d_in[8];
  const float* Wd1  = (const float*)d_in[9];
  const float* bd1  = (const float*)d_in[10];
  const float* Wd2  = (const float*)d_in[11];
  const float* bd2  = (const float*)d_in[12];
  float* out = (float*)d_out;

  _Float16* wh  = (_Float16*)d_ws;
  float*    bsv = (float*)((char*)d_ws + (size_t)WH_TOTAL_HALVES * 2);

  prep_kernel<<<63, 256, 0, stream>>>(Wih0, Whh0, bih0, bhh0, Wih1, Whh1, bih1, bhh1, wh, bsv);
  // 16384 rows / 32 per block = 512 blocks (2 rounds at 1 block/CU)
  lstm_kernel<<<512, 512, 0, stream>>>(x, wh, bsv, Wd1, bd1, Wd2, bd2, out);
}

// Round 12
// 763.864 us; speedup vs baseline: 2.5761x; 1.1000x over previous
//
#include <hip/hip_runtime.h>
#include <hip/hip_fp16.h>

// ============================================================================
// 2-layer LSTM (B=16384, T=128, F=12, H1=64, H2=128) + head, round 12.
// R11 audit: trans ops (10/output, 16cy each wave-wide) ~70% of VALU busy;
// qtrans4 DPP 192 VALU/wave-step. Changes:
//  - SWAPPED MFMA OPERANDS: gates^T = W * state^T. A/B frag lane-maps are
//    symmetric -> same packed weights, same LDS reads, just swapped args.
//    D now has p=4h+g on the REG axis: acc[4G+j] = gate j of one hidden,
//    batch = lane. 4 gates of a cell in one lane's regs -> qtrans4 DELETED,
//    gate type is a compile-time reg slot.
//  - SHARED-RCP cell math: c'=[c*A*Gp+B*Gm]/(B*A*Gp); h=(e2c-1)/((1+eo)(1+e2c)).
//    7 trans/output (5 exp + 2 rcp) vs 10. tanh(c) input clamped +-15 (exact).
//  - Bias via MFMA C-operand (bias4 L0 / bias16 L1 pinned VGPRs): no init movs.
//  - Weights pinned "+a" (AGPR-native A-operand, no copy churn).
// Config: 512 thr / 8 waves, R=32, 512 blocks, 1 barrier/timestep (R10/R11).
// ============================================================================

#define T_STEPS 128
#define F_IN    12
#define R       32      // batch rows per block
#define S0H     136     // st0 row stride in halves (272B = 17*16B)
#define S1H     392     // st1 row stride in halves (784B = 49*16B): 2 x 192 + pad

#define WF0_H8  (16*3*64)
#define WF1_H8  (16*12*64)
#define WH_TOTAL_HALVES ((WF0_H8 + WF1_H8)*8)   // 245760 B

typedef _Float16 half8 __attribute__((ext_vector_type(8)));
typedef _Float16 half4 __attribute__((ext_vector_type(4)));
typedef float   floatx4  __attribute__((ext_vector_type(4)));
typedef float   floatx16 __attribute__((ext_vector_type(16)));
typedef int     intx4  __attribute__((ext_vector_type(4)));

__device__ __forceinline__ float vexp2(float x){
  float r; asm("v_exp_f32 %0, %1" : "=v"(r) : "v"(x)); return r;
}
__device__ __forceinline__ float vrcp(float x){
  float r; asm("v_rcp_f32 %0, %1" : "=v"(r) : "v"(x)); return r;
}

// Fused LSTM cell: c' = sig(f)*c + sig(i)*tanh(g); h = sig(o)*tanh(c').
// Shared-rcp form: 5 exp + 2 rcp. Preacts bounded (~17) by weight norms ->
// no overflow; tanh(c) input clamped +-15 (tanh saturates exactly in fp32).
__device__ __forceinline__ float lstm_cell(float pi, float pf, float pg, float po, float& c){
  const float NL2E  = -1.4426950408889634f;
  const float P2L2E =  2.8853900817779268f;
  float ei = vexp2(NL2E * pi);          // e^-i
  float ef = vexp2(NL2E * pf);          // e^-f
  float gp = vexp2(P2L2E * pg);         // e^{2g}
  float eo = vexp2(NL2E * po);          // e^-o
  float A   = 1.0f + ei;
  float Bf  = 1.0f + ef;
  float Gp  = 1.0f + gp;
  float Gm  = gp - 1.0f;
  float AGp = A * Gp;
  float num = fmaf(c, AGp, Bf * Gm);    // c*A*Gp + B*(e2g-1)
  float cn  = num * vrcp(Bf * AGp);
  c = cn;
  float tcl = fminf(fmaxf(cn, -15.0f), 15.0f);
  float e2c = vexp2(P2L2E * tcl);       // e^{2c'}
  float hd  = (1.0f + eo) * (1.0f + e2c);
  return (e2c - 1.0f) * vrcp(hd);
}

// ---------------------------------------------------------------------------
// Prep (identical to R11, correctness-validated): PERMUTED cols p=4h+g.
// L0 frags [ct16][kt3][lane]: p=ct*16+(l&15), k=kt*32+(l>>4)*8+j
// L1 frags [ct16][kt12][lane]: p=ct*32+(l&31), k=kt*16+(l>>5)*8+j
// bs[0..256): bias0 in p-order; bs[256..768): bias1 in p-order.
// ---------------------------------------------------------------------------
__global__ void prep_kernel(const float* __restrict__ Wih0, const float* __restrict__ Whh0,
                            const float* __restrict__ bih0, const float* __restrict__ bhh0,
                            const float* __restrict__ Wih1, const float* __restrict__ Whh1,
                            const float* __restrict__ bih1, const float* __restrict__ bhh1,
                            _Float16* __restrict__ wh, float* __restrict__ bs) {
  int tid = blockIdx.x * 256 + threadIdx.x;
  if (tid < WF0_H8) {
    int lane = tid & 63; int kt = (tid >> 6) % 3; int ct = tid / (64*3);
    int p = ct*16 + (lane & 15);
    int col = (p & 3)*64 + (p >> 2);
    int kbase = kt*32 + (lane >> 4)*8;
    #pragma unroll
    for (int j = 0; j < 8; ++j) {
      int k = kbase + j; float w = 0.0f;
      if (k < 12) w = Wih0[col*12 + k];
      else if (k < 76) w = Whh0[col*64 + (k-12)];
      wh[tid*8 + j] = (_Float16)w;
    }
  } else if (tid < WF0_H8 + WF1_H8) {
    int t2 = tid - WF0_H8;
    int lane = t2 & 63; int kt = (t2 >> 6) % 12; int ct = t2 / (64*12);
    int p = ct*32 + (lane & 31);
    int col = (p & 3)*128 + (p >> 2);
    int kbase = kt*16 + (lane >> 5)*8;
    #pragma unroll
    for (int j = 0; j < 8; ++j) {
      int k = kbase + j;
      float w = (k < 64) ? Wih1[col*64 + k] : Whh1[col*128 + (k-64)];
      wh[WF0_H8*8 + t2*8 + j] = (_Float16)w;
    }
  } else if (tid < WF0_H8 + WF1_H8 + 768) {
    int t3 = tid - (WF0_H8 + WF1_H8);
    if (t3 < 256) { int col = (t3 & 3)*64 + (t3 >> 2);  bs[t3] = bih0[col] + bhh0[col]; }
    else { int p1 = t3 - 256; int col = (p1 & 3)*128 + (p1 >> 2); bs[t3] = bih1[col] + bhh1[col]; }
  }
}

// ---------------------------------------------------------------------------
// Main: 512 threads (8 waves), 32 rows/block, 512 blocks.
// st0[2][32][136]h: per row [x12|h0 64|zeros..95|pad].
// st1[32][392]h: per row, parity block pr at +pr*192: [h0(pr) 64 | h1(pr^1) 128].
// Wave w: L0 coltiles {2w,2w+1} (swapped: weights=A), L1 32x32 coltiles {2w,2w+1}.
// After MFMA: lane = batch row; regs = p (gate j, hidden): no cross-lane moves.
// ---------------------------------------------------------------------------
__global__ __launch_bounds__(512, 1)
void lstm_kernel(const float* __restrict__ x, const _Float16* __restrict__ wh,
                 const float* __restrict__ bs,
                 const float* __restrict__ Wd1, const float* __restrict__ bd1,
                 const float* __restrict__ Wd2, const float* __restrict__ bd2,
                 float* __restrict__ out) {
  __shared__ __align__(16) _Float16 st0[2*R*S0H];   // 17408 B
  __shared__ __align__(16) _Float16 st1[R*S1H];     // 25088 B
  __shared__ float hbuf[R*132];                     // 16896 B
  __shared__ float red[R*17];                       // 2176 B  -> ~60 KB

  const int tid  = threadIdx.x;
  const int w    = tid >> 6;             // 0..7
  const int lane = tid & 63;
  const int l15  = lane & 15;
  const int l31  = lane & 31;
  const int lg   = lane >> 4;            // 0..3
  const int hi5  = lane >> 5;            // 0..1
  const int rowbase = blockIdx.x * R;

  // ---- weights -> AGPRs, pinned; bias -> VGPRs (MFMA C-operands) ----
  const intx4* whi = (const intx4*)wh;
  intx4 wb0i[2][3];
  #pragma unroll
  for (int i = 0; i < 2; ++i)
    #pragma unroll
    for (int kt = 0; kt < 3; ++kt) wb0i[i][kt] = whi[((2*w+i)*3 + kt)*64 + lane];
  intx4 wb1i[2][12];
  #pragma unroll
  for (int i = 0; i < 2; ++i)
    #pragma unroll
    for (int kt = 0; kt < 12; ++kt) wb1i[i][kt] = whi[WF0_H8 + ((2*w+i)*12 + kt)*64 + lane];
  floatx4 bias4[2];
  #pragma unroll
  for (int i = 0; i < 2; ++i)
    #pragma unroll
    for (int j = 0; j < 4; ++j) bias4[i][j] = bs[(2*w+i)*16 + lg*4 + j];
  floatx16 bias16[2];
  #pragma unroll
  for (int i = 0; i < 2; ++i)
    #pragma unroll
    for (int reg = 0; reg < 16; ++reg) {
      int pl = (reg & 3) + 8*(reg >> 2) + 4*hi5;
      bias16[i][reg] = bs[256 + (2*w+i)*32 + pl];
    }

  // Cell state: L0 (batch 16mt+l15, hidden 8w+4i+lg); L1 (batch l31, hidden 16w+8i+2G+hi5).
  float c0s[2][2] = {{0.0f,0.0f},{0.0f,0.0f}};
  float c1s[2][4] = {{0.0f,0.0f,0.0f,0.0f},{0.0f,0.0f,0.0f,0.0f}};

  // ---- zero-init LDS ----
  for (int i = tid; i < (2*R*S0H)/2; i += 512) ((int*)st0)[i] = 0;
  for (int i = tid; i < (R*S1H)/2;   i += 512) ((int*)st1)[i] = 0;
  __syncthreads();
  const int xr = tid / 3, xq = tid % 3;     // 96 threads stage x
  if (tid < 96) {
    float4 v0 = *(const float4*)&x[((size_t)(rowbase + xr)*T_STEPS + 0)*F_IN + xq*4];
    float4 v1 = *(const float4*)&x[((size_t)(rowbase + xr)*T_STEPS + 1)*F_IN + xq*4];
    half4 h40 = {(_Float16)v0.x, (_Float16)v0.y, (_Float16)v0.z, (_Float16)v0.w};
    half4 h41 = {(_Float16)v1.x, (_Float16)v1.y, (_Float16)v1.z, (_Float16)v1.w};
    *(half4*)&st0[xr*S0H + xq*4]         = h40;
    *(half4*)&st0[R*S0H + xr*S0H + xq*4] = h41;
  }
  __syncthreads();

  // ---- layer-0 step (16x16 swapped), M-tile mt; acc[j] = gate j, hidden 8w+4i+lg ----
  auto do_A = [&](int tt, int mt){
    const int prA = tt & 1;
    const int rb = prA*(R*S0H) + (16*mt + l15)*S0H + lg*8;
    floatx4 acc0 = bias4[0], acc1 = bias4[1];
    #pragma unroll
    for (int kt = 0; kt < 3; ++kt) {
      half8 sf = *(const half8*)&st0[rb + kt*32];
      acc0 = __builtin_amdgcn_mfma_f32_16x16x32_f16(__builtin_bit_cast(half8, wb0i[0][kt]), sf, acc0, 0, 0, 0);
      acc1 = __builtin_amdgcn_mfma_f32_16x16x32_f16(__builtin_bit_cast(half8, wb0i[1][kt]), sf, acc1, 0, 0, 0);
    }
    #pragma unroll
    for (int i = 0; i < 2; ++i) {
      floatx4 ac = i ? acc1 : acc0;
      float h = lstm_cell(ac[0], ac[1], ac[2], ac[3], c0s[i][mt]);
      _Float16 hh = (_Float16)h;
      const int hid = 8*w + 4*i + lg;
      st0[(prA^1)*(R*S0H) + (16*mt+l15)*S0H + 12 + hid] = hh;
      st1[(16*mt+l15)*S1H + prA*192 + hid]              = hh;
    }
  };

  // ---- layer-1 step (32x32x16 swapped); reg 4G+j = gate j, hidden 16w+8i+2G+hi5 ----
  auto do_C = [&](int tt){
    const int pr = tt & 1;
    const int rb = l31*S1H + pr*192 + hi5*8;
    floatx16 acc0 = bias16[0], acc1 = bias16[1];
    #pragma unroll
    for (int kt = 0; kt < 12; ++kt) {
      half8 sf = *(const half8*)&st1[rb + kt*16];
      acc0 = __builtin_amdgcn_mfma_f32_32x32x16_f16(__builtin_bit_cast(half8, wb1i[0][kt]), sf, acc0, 0, 0, 0);
      acc1 = __builtin_amdgcn_mfma_f32_32x32x16_f16(__builtin_bit_cast(half8, wb1i[1][kt]), sf, acc1, 0, 0, 0);
    }
    const int wbse = l31*S1H + (pr^1)*192 + 64 + 16*w;
    #pragma unroll
    for (int i = 0; i < 2; ++i) {
      #pragma unroll
      for (int G = 0; G < 4; ++G) {
        floatx4 ac;
        if (i) { ac[0]=acc1[4*G+0]; ac[1]=acc1[4*G+1]; ac[2]=acc1[4*G+2]; ac[3]=acc1[4*G+3]; }
        else   { ac[0]=acc0[4*G+0]; ac[1]=acc0[4*G+1]; ac[2]=acc0[4*G+2]; ac[3]=acc0[4*G+3]; }
        float h = lstm_cell(ac[0], ac[1], ac[2], ac[3], c1s[i][G]);
        const int hid = 8*i + 2*G + hi5;
        st1[wbse + hid] = (_Float16)h;
        if (tt == T_STEPS - 1) hbuf[l31*132 + 16*w + hid] = h;
      }
    }
  };

  // ---- prologue: A(0) both M-tiles; loop phases {C(t) || A(t+1)}, 1 barrier ----
  do_A(0, 0); do_A(0, 1);
  __syncthreads();

  for (int t = 0; t < T_STEPS; t += 2) {
    // Pin weights in AGPRs and biases in VGPRs (forbid remat/refetch).
    #pragma unroll
    for (int i = 0; i < 2; ++i) {
      #pragma unroll
      for (int kt = 0; kt < 3; ++kt) asm volatile("" : "+a"(wb0i[i][kt]));
      #pragma unroll
      for (int kt = 0; kt < 12; ++kt) asm volatile("" : "+a"(wb1i[i][kt]));
      asm volatile("" : "+v"(bias4[i]), "+v"(bias16[i]));
    }

    #pragma unroll
    for (int hl = 0; hl < 2; ++hl) {
      const int tt = t + hl;
      const int pr = hl;               // tt & 1
      float4 xv = {0.0f, 0.0f, 0.0f, 0.0f};
      const bool dopre = (tt + 2 < T_STEPS);
      if (tid < 96 && dopre)           // issue x(tt+2) load early
        xv = *(const float4*)&x[((size_t)(rowbase + xr)*T_STEPS + (tt+2))*F_IN + xq*4];

      do_C(tt);
      if (tt + 1 < T_STEPS) { do_A(tt+1, 0); do_A(tt+1, 1); }

      if (tid < 96 && dopre) {
        half4 h4 = {(_Float16)xv.x, (_Float16)xv.y, (_Float16)xv.z, (_Float16)xv.w};
        *(half4*)&st0[pr*(R*S0H) + xr*S0H + xq*4] = h4;
      }
      __syncthreads();
    }
  }

  // ---------- Head: out[r] = b_d2 + Wd2 @ (b_d1 + Wd1 @ h1[r]) ----------
  {
    const int hr = tid & 31, jg = tid >> 5;   // 16 j-groups of 8
    float partial = 0.0f;
    #pragma unroll
    for (int jj = 0; jj < 8; ++jj) {
      int j = jg*8 + jj;
      float dacc = bd1[j];
      const float4* wrow = (const float4*)&Wd1[j*128];
      #pragma unroll 8
      for (int k4 = 0; k4 < 32; ++k4) {
        float4 wv = wrow[k4];
        const float4 hv = *(const float4*)&hbuf[hr*132 + k4*4];
        dacc = fmaf(wv.x, hv.x, dacc); dacc = fmaf(wv.y, hv.y, dacc);
        dacc = fmaf(wv.z, hv.z, dacc); dacc = fmaf(wv.w, hv.w, dacc);
      }
      partial = fmaf(Wd2[j], dacc, partial);
    }
    red[hr*17 + jg] = partial;
  }
  __syncthreads();
  if (tid < R) {
    float ssum = bd2[0];
    #pragma unroll
    for (int k = 0; k < 16; ++k) ssum += red[tid*17 + k];
    out[rowbase + tid] = ssum;
  }
}

extern "C" void kernel_launch(void* const* d_in, const int* in_sizes, int n_in,
                              void* d_out, int out_size, void* d_ws, size_t ws_size,
                              hipStream_t stream) {
  const float* x    = (const float*)d_in[0];
  const float* Wih0 = (const float*)d_in[1];
  const float* Whh0 = (const float*)d_in[2];
  const float* bih0 = (const float*)d_in[3];
  const float* bhh0 = (const float*)d_in[4];
  const float* Wih1 = (const float*)d_in[5];
  const float* Whh1 = (const float*)d_in[6];
  const float* bih1 = (const float*)d_in[7];
  const float* bhh1 = (const float*)d_in[8];
  const float* Wd1  = (const float*)d_in[9];
  const float* bd1  = (const float*)d_in[10];
  const float* Wd2  = (const float*)d_in[11];
  const float* bd2  = (const float*)d_in[12];
  float* out = (float*)d_out;

  _Float16* wh  = (_Float16*)d_ws;
  float*    bsv = (float*)((char*)d_ws + (size_t)WH_TOTAL_HALVES * 2);

  prep_kernel<<<63, 256, 0, stream>>>(Wih0, Whh0, bih0, bhh0, Wih1, Whh1, bih1, bhh1, wh, bsv);
  // 16384 rows / 32 per block = 512 blocks (2 rounds at 1 block/CU)
  lstm_kernel<<<512, 512, 0, stream>>>(x, wh, bsv, Wd1, bd1, Wd2, bd2, out);
}